// Round 9
// baseline (152.608 us; speedup 1.0000x reference)
//
#include <hip/hip_runtime.h>
#include <math.h>

#define KNN 16
#define EPS_F 0.001f
#define BLK 256
#define SCH 16             // sample chunks
#define SSTRIDE 8          // sample every 8th candidate

#define REP16(M) M(0) M(1) M(2) M(3) M(4) M(5) M(6) M(7) \
                 M(8) M(9) M(10) M(11) M(12) M(13) M(14) M(15)

// ---- int compare-exchange on packed keys (v_min_i32/v_max_i32) ----
#define CEAI(p,a,b) { int _lo = min(p##a, p##b); int _hi = max(p##a, p##b); p##a = _lo; p##b = _hi; }
#define CEDI(p,a,b) { int _lo = min(p##a, p##b); int _hi = max(p##a, p##b); p##a = _hi; p##b = _lo; }

// bitonic sort-16 ascending (80 CE)
#define SORT16I(p) \
  CEAI(p,0,1) CEDI(p,2,3) CEAI(p,4,5) CEDI(p,6,7) CEAI(p,8,9) CEDI(p,10,11) CEAI(p,12,13) CEDI(p,14,15) \
  CEAI(p,0,2) CEAI(p,1,3) CEDI(p,4,6) CEDI(p,5,7) CEAI(p,8,10) CEAI(p,9,11) CEDI(p,12,14) CEDI(p,13,15) \
  CEAI(p,0,1) CEAI(p,2,3) CEDI(p,4,5) CEDI(p,6,7) CEAI(p,8,9) CEAI(p,10,11) CEDI(p,12,13) CEDI(p,14,15) \
  CEAI(p,0,4) CEAI(p,1,5) CEAI(p,2,6) CEAI(p,3,7) CEDI(p,8,12) CEDI(p,9,13) CEDI(p,10,14) CEDI(p,11,15) \
  CEAI(p,0,2) CEAI(p,1,3) CEAI(p,4,6) CEAI(p,5,7) CEDI(p,8,10) CEDI(p,9,11) CEDI(p,12,14) CEDI(p,13,15) \
  CEAI(p,0,1) CEAI(p,2,3) CEAI(p,4,5) CEAI(p,6,7) CEDI(p,8,9) CEDI(p,10,11) CEDI(p,12,13) CEDI(p,14,15) \
  CEAI(p,0,8) CEAI(p,1,9) CEAI(p,2,10) CEAI(p,3,11) CEAI(p,4,12) CEAI(p,5,13) CEAI(p,6,14) CEAI(p,7,15) \
  CEAI(p,0,4) CEAI(p,1,5) CEAI(p,2,6) CEAI(p,3,7) CEAI(p,8,12) CEAI(p,9,13) CEAI(p,10,14) CEAI(p,11,15) \
  CEAI(p,0,2) CEAI(p,1,3) CEAI(p,4,6) CEAI(p,5,7) CEAI(p,8,10) CEAI(p,9,11) CEAI(p,12,14) CEAI(p,13,15) \
  CEAI(p,0,1) CEAI(p,2,3) CEAI(p,4,5) CEAI(p,6,7) CEAI(p,8,9) CEAI(p,10,11) CEAI(p,12,13) CEAI(p,14,15)

// bitonic cleanup: bitonic -> ascending (32 CE)
#define RESORT16I(p) \
  CEAI(p,0,8) CEAI(p,1,9) CEAI(p,2,10) CEAI(p,3,11) CEAI(p,4,12) CEAI(p,5,13) CEAI(p,6,14) CEAI(p,7,15) \
  CEAI(p,0,4) CEAI(p,1,5) CEAI(p,2,6) CEAI(p,3,7) CEAI(p,8,12) CEAI(p,9,13) CEAI(p,10,14) CEAI(p,11,15) \
  CEAI(p,0,2) CEAI(p,1,3) CEAI(p,4,6) CEAI(p,5,7) CEAI(p,8,10) CEAI(p,9,11) CEAI(p,12,14) CEAI(p,13,15) \
  CEAI(p,0,1) CEAI(p,2,3) CEAI(p,4,5) CEAI(p,6,7) CEAI(p,8,9) CEAI(p,10,11) CEAI(p,12,13) CEAI(p,14,15)

// keep 16 smallest of (sorted r) U (sorted x)
#define MERGE16I(r,x) \
  r##0=min(r##0,x##15); r##1=min(r##1,x##14); r##2=min(r##2,x##13); r##3=min(r##3,x##12); \
  r##4=min(r##4,x##11); r##5=min(r##5,x##10); r##6=min(r##6,x##9);  r##7=min(r##7,x##8);  \
  r##8=min(r##8,x##7);  r##9=min(r##9,x##6);  r##10=min(r##10,x##5); r##11=min(r##11,x##4); \
  r##12=min(r##12,x##3); r##13=min(r##13,x##2); r##14=min(r##14,x##1); r##15=min(r##15,x##0); \
  RESORT16I(r)

// folded distance: P.xyz = -2*bary_j, P.w = |bary_j|^2 ; q = (bary_i, |bary_i|^2)
__device__ __forceinline__ float distf(float4 q, float4 P) {
    return fmaf(q.x, P.x, fmaf(q.y, P.y, fmaf(q.z, P.z, q.w + P.w)));
}
// truncate mantissa to 9 bits, candidate index in low 14 bits
__device__ __forceinline__ int packkey(float d2, int j) {
    return (__float_as_int(d2) & 0xFFFFC000) | j;
}

// ---------------- Kernel 1: per-face prep ----------------
__global__ __launch_bounds__(BLK) void prep_kernel(
    const float* __restrict__ verts, const int* __restrict__ faces,
    float4* __restrict__ baryq, float4* __restrict__ baryqm,
    float* __restrict__ nrm, float* __restrict__ p0s, int F)
{
    int f = blockIdx.x * BLK + threadIdx.x;
    if (f >= F) return;
    int i0 = faces[3*f+0], i1 = faces[3*f+1], i2 = faces[3*f+2];
    float ax = verts[3*i0+0], ay = verts[3*i0+1], az = verts[3*i0+2];
    float bx = verts[3*i1+0], by = verts[3*i1+1], bz = verts[3*i1+2];
    float cx = verts[3*i2+0], cy = verts[3*i2+1], cz = verts[3*i2+2];
    float gx = (ax + bx + cx) / 3.0f;
    float gy = (ay + by + cy) / 3.0f;
    float gz = (az + bz + cz) / 3.0f;
    float sq = gx*gx + gy*gy + gz*gz;
    baryq[f]  = make_float4(gx, gy, gz, sq);
    baryqm[f] = make_float4(-2.0f*gx, -2.0f*gy, -2.0f*gz, sq);
    float e1x = bx-ax, e1y = by-ay, e1z = bz-az;
    float e2x = cx-ax, e2y = cy-ay, e2z = cz-az;
    float nx = e1y*e2z - e1z*e2y;
    float ny = e1z*e2x - e1x*e2z;
    float nz = e1x*e2y - e1y*e2x;
    float len = sqrtf(nx*nx + ny*ny + nz*nz);
    float dn = fmaxf(len, 1e-12f);
    nrm[3*f+0] = nx/dn; nrm[3*f+1] = ny/dn; nrm[3*f+2] = nz/dn;
    p0s[3*f+0] = ax; p0s[3*f+1] = ay; p0s[3*f+2] = az;
}

// -------- Kernel 2: sampled top-16 keys (LDS-staged candidates, R6 style) --
__global__ __launch_bounds__(BLK) void knn_sample(
    const float4* __restrict__ baryq, const float4* __restrict__ baryqm,
    int* __restrict__ samp_k, int F, int SLEN)
{
    extern __shared__ float4 sb[];
    int tid = threadIdx.x;
    int qi = blockIdx.x * BLK + tid;
    float4 q = baryq[min(qi, F-1)];
    #define DECLR(m) int r##m = 0x7fffffff;
    REP16(DECLR)
    #undef DECLR
    int sbase = blockIdx.y * SLEN;
    if (tid < SLEN) {
        int j = (sbase + tid) * SSTRIDE;
        sb[tid] = (j < F) ? baryqm[j] : make_float4(0.f, 0.f, 0.f, INFINITY);
    }
    __syncthreads();
    #pragma unroll 1
    for (int g = 0; g < SLEN; g += 16) {
        #define MKK(m) int x##m = packkey(distf(q, sb[g+(m)]), (sbase+g+(m))*SSTRIDE);
        REP16(MKK)
        #undef MKK
        SORT16I(x)
        MERGE16I(r, x)
    }
    if (qi < F) {
        size_t cb = (size_t)blockIdx.y * KNN * F + qi;
        #define STR(m) samp_k[cb + (size_t)(m) * F] = r##m;
        REP16(STR)
        #undef STR
    }
}

// -------- Kernel 3: merge sample lists -> threshold key; zero cnt and out --
__global__ __launch_bounds__(BLK) void merge_T(
    const int* __restrict__ samp_k, int* __restrict__ Tkey,
    int* __restrict__ cnt, float* __restrict__ out, int F)
{
    int qi = blockIdx.x * BLK + threadIdx.x;
    if (blockIdx.x == 0 && threadIdx.x == 0) out[0] = 0.0f;
    if (qi >= F) return;
    #define LDR(m) int r##m = samp_k[(size_t)(m) * F + qi];
    REP16(LDR)
    #undef LDR
    for (int c = 1; c < SCH; ++c) {
        size_t cb = (size_t)c * KNN * F + qi;
        #define LDX(m) int x##m = samp_k[cb + (size_t)(m) * F];
        REP16(LDX)
        #undef LDX
        MERGE16I(r, x)
    }
    Tkey[qi] = r15;          // 16th-smallest sample key >= true 16th key
    cnt[qi] = 0;
}

// -------- Kernel 4: threshold collect -> global-direct survivor writes -----
// grid (qBlocks, nCChunk ~49). No LDS at all: 8 blocks/CU, 32 waves/CU.
// Survive prob ~1.3e-3: atomic+store path runs on ~8% of wave-steps.
__global__ __launch_bounds__(BLK, 8) void collect_kernel(
    const float4* __restrict__ baryq, const float4* __restrict__ baryqm,
    const int* __restrict__ Tkey, int* __restrict__ cnt,
    int* __restrict__ buf, int F, int CLEN, int CAP)
{
    int tid = threadIdx.x;
    int qi = blockIdx.x * BLK + tid;
    bool active = qi < F;
    int qc = min(qi, F-1);
    float4 q = baryq[qc];
    int T = active ? Tkey[qc] : 0x80000000;   // inactive lanes collect nothing
    int jb = blockIdx.y * CLEN;
    int je = min(jb + CLEN, F);
    int jfull = jb + ((je - jb) & ~15);
    #pragma unroll 1
    for (int base = jb; base < jfull; base += 16) {
        const float4* tp = baryqm + base;
        #define CSTEP(m) { float4 P = tp[m]; \
            int key = packkey(distf(q, P), base + (m)); \
            if (key <= T) { \
                int pos = atomicAdd(&cnt[qi], 1); \
                if (pos < CAP) buf[(size_t)qi * CAP + pos] = key; } }
        REP16(CSTEP)
        #undef CSTEP
    }
    for (int j = jfull; j < je; ++j) {        // tail (F%16!=0 only)
        float4 P = baryqm[j];
        int key = packkey(distf(q, P), j);
        if (key <= T) {
            int pos = atomicAdd(&cnt[qi], 1);
            if (pos < CAP) buf[(size_t)qi * CAP + pos] = key;
        }
    }
}

// -------- Kernel 5: fused exact top-16 + penetration + global reduce -------
__device__ __forceinline__ bool edge_test(
    float nx, float ny, float nz, float px, float py, float pz,
    float ax, float ay, float az, float bx, float by, float bz)
{
    float denom = nx*(bx-ax) + ny*(by-ay) + nz*(bz-az);
    if (fabsf(denom) < EPS_F) return false;
    float numer = nx*(px-ax) + ny*(py-ay) + nz*(pz-az);
    float t = numer / denom;
    return (t > 0.0f) && (t < 1.0f);
}

__global__ __launch_bounds__(BLK) void select_pen(
    const int* __restrict__ buf, const int* __restrict__ cnt,
    const float* __restrict__ verts, const int* __restrict__ faces,
    const float* __restrict__ prob, const float* __restrict__ nrm,
    const float* __restrict__ p0s, float* __restrict__ out,
    int F, int CAP)
{
    int qi = blockIdx.x * BLK + threadIdx.x;
    float val = 0.0f;
    if (qi < F) {
        int n = min(cnt[qi], CAP);
        const int* row = buf + (size_t)qi * CAP;
        #define DECLR(m) int r##m = 0x7fffffff;
        REP16(DECLR)
        #undef DECLR
        #pragma unroll 1
        for (int t = 0; t < n; t += 16) {
            #define LSEL(m) int x##m; { int v = row[t + (m)]; \
                x##m = (t + (m) < n) ? v : 0x7fffffff; }
            REP16(LSEL)
            #undef LSEL
            SORT16I(x)
            MERGE16I(r, x)
        }
        // penetration over the exact top-16 (#{key<=T} >= 16 by construction)
        float nx = nrm[3*qi+0], ny = nrm[3*qi+1], nz = nrm[3*qi+2];
        float px = p0s[3*qi+0], py = p0s[3*qi+1], pz = p0s[3*qi+2];
        #define PENM(m) { int j = r##m & 0x3FFF; \
            if (j != qi && j < F) { \
                int j0 = faces[3*j+0], j1 = faces[3*j+1], j2 = faces[3*j+2]; \
                float ax = verts[3*j0+0], ay = verts[3*j0+1], az = verts[3*j0+2]; \
                float bx = verts[3*j1+0], by = verts[3*j1+1], bz = verts[3*j1+2]; \
                float cx = verts[3*j2+0], cy = verts[3*j2+1], cz = verts[3*j2+2]; \
                bool hit = edge_test(nx,ny,nz, px,py,pz, ax,ay,az, bx,by,bz) \
                        || edge_test(nx,ny,nz, px,py,pz, bx,by,bz, cx,cy,cz) \
                        || edge_test(nx,ny,nz, px,py,pz, cx,cy,cz, ax,ay,az); \
                if (hit) val += prob[j]; } }
        REP16(PENM)
        #undef PENM
    }
    __shared__ float red[BLK];
    red[threadIdx.x] = val;
    __syncthreads();
    #pragma unroll
    for (int s = BLK/2; s > 0; s >>= 1) {
        if (threadIdx.x < s) red[threadIdx.x] += red[threadIdx.x + s];
        __syncthreads();
    }
    if (threadIdx.x == 0) atomicAdd(out, red[0] / (float)F);
}

extern "C" void kernel_launch(void* const* d_in, const int* in_sizes, int n_in,
                              void* d_out, int out_size, void* d_ws, size_t ws_size,
                              hipStream_t stream)
{
    const float* verts = (const float*)d_in[0];
    const int*   faces = (const int*)d_in[1];
    const float* prob  = (const float*)d_in[2];
    float* out = (float*)d_out;
    int F = in_sizes[2];

    size_t off = 0;
    auto carve = [&](size_t bytes) {
        size_t cur = off;
        off += (bytes + 255) & ~(size_t)255;
        return cur;
    };
    char* w = (char*)d_ws;
    int qBlocks = (F + BLK - 1) / BLK;
    float4* baryq  = (float4*)(w + carve((size_t)F * sizeof(float4)));
    float4* baryqm = (float4*)(w + carve((size_t)F * sizeof(float4)));
    float*  nrm    = (float*)(w + carve((size_t)F * 3 * sizeof(float)));
    float*  p0s    = (float*)(w + carve((size_t)F * 3 * sizeof(float)));
    int*    Tkey   = (int*)(w + carve((size_t)F * sizeof(int)));
    int*    cnt    = (int*)(w + carve((size_t)F * sizeof(int)));
    int*    samp_k = (int*)(w + carve((size_t)SCH * KNN * F * sizeof(int)));

    // survivor buffer: adaptive capacity from remaining ws (+pad for LSEL overread)
    size_t remain = (ws_size > off) ? (ws_size - off) : 0;
    int CAP = (int)((remain - 256) / ((size_t)F * sizeof(int)));
    if (CAP > 448) CAP = 448;
    if (CAP < 320) CAP = 320;
    CAP &= ~15;
    int* buf = (int*)(w + carve((size_t)F * CAP * sizeof(int) + 256));

    int nSamp = (F + SSTRIDE - 1) / SSTRIDE;
    int SLEN = ((nSamp + SCH - 1) / SCH + 15) & ~15;          // 80 at F=10000
    // collect grid: one scheduling round (<= 8 blocks/CU * 256 CU)
    int nChTarget = (2048 / qBlocks > 1) ? (2048 / qBlocks) : 1; // 51 at F=10000
    int CLEN = (((F + nChTarget - 1) / nChTarget) + 15) & ~15;   // 208
    int nCChunk = (F + CLEN - 1) / CLEN;                         // 49

    prep_kernel<<<qBlocks, BLK, 0, stream>>>(verts, faces, baryq, baryqm, nrm, p0s, F);
    knn_sample<<<dim3(qBlocks, SCH), BLK, SLEN * sizeof(float4), stream>>>(
        baryq, baryqm, samp_k, F, SLEN);
    merge_T<<<qBlocks, BLK, 0, stream>>>(samp_k, Tkey, cnt, out, F);
    collect_kernel<<<dim3(qBlocks, nCChunk), BLK, 0, stream>>>(
        baryq, baryqm, Tkey, cnt, buf, F, CLEN, CAP);
    select_pen<<<qBlocks, BLK, 0, stream>>>(
        buf, cnt, verts, faces, prob, nrm, p0s, out, F, CAP);
}

// Round 10
// 90.388 us; speedup vs baseline: 1.6884x; 1.6884x over previous
//
#include <hip/hip_runtime.h>
#include <math.h>

#define KNN 16
#define EPS_F 0.001f
#define BLK 256
#define RCAP 17            // register stash slots per lane
#define SCH 8              // sample chunks
#define SSTRIDE 8          // sample every 8th candidate

#define REP16(M) M(0) M(1) M(2) M(3) M(4) M(5) M(6) M(7) \
                 M(8) M(9) M(10) M(11) M(12) M(13) M(14) M(15)
#define REP17(M) REP16(M) M(16)

// ---- int compare-exchange on packed keys (v_min_i32/v_max_i32) ----
#define CEAI(p,a,b) { int _lo = min(p##a, p##b); int _hi = max(p##a, p##b); p##a = _lo; p##b = _hi; }
#define CEDI(p,a,b) { int _lo = min(p##a, p##b); int _hi = max(p##a, p##b); p##a = _hi; p##b = _lo; }

// bitonic sort-16 ascending (80 CE)
#define SORT16I(p) \
  CEAI(p,0,1) CEDI(p,2,3) CEAI(p,4,5) CEDI(p,6,7) CEAI(p,8,9) CEDI(p,10,11) CEAI(p,12,13) CEDI(p,14,15) \
  CEAI(p,0,2) CEAI(p,1,3) CEDI(p,4,6) CEDI(p,5,7) CEAI(p,8,10) CEAI(p,9,11) CEDI(p,12,14) CEDI(p,13,15) \
  CEAI(p,0,1) CEAI(p,2,3) CEDI(p,4,5) CEDI(p,6,7) CEAI(p,8,9) CEAI(p,10,11) CEDI(p,12,13) CEDI(p,14,15) \
  CEAI(p,0,4) CEAI(p,1,5) CEAI(p,2,6) CEAI(p,3,7) CEDI(p,8,12) CEDI(p,9,13) CEDI(p,10,14) CEDI(p,11,15) \
  CEAI(p,0,2) CEAI(p,1,3) CEAI(p,4,6) CEAI(p,5,7) CEDI(p,8,10) CEDI(p,9,11) CEDI(p,12,14) CEDI(p,13,15) \
  CEAI(p,0,1) CEAI(p,2,3) CEAI(p,4,5) CEAI(p,6,7) CEDI(p,8,9) CEDI(p,10,11) CEDI(p,12,13) CEDI(p,14,15) \
  CEAI(p,0,8) CEAI(p,1,9) CEAI(p,2,10) CEAI(p,3,11) CEAI(p,4,12) CEAI(p,5,13) CEAI(p,6,14) CEAI(p,7,15) \
  CEAI(p,0,4) CEAI(p,1,5) CEAI(p,2,6) CEAI(p,3,7) CEAI(p,8,12) CEAI(p,9,13) CEAI(p,10,14) CEAI(p,11,15) \
  CEAI(p,0,2) CEAI(p,1,3) CEAI(p,4,6) CEAI(p,5,7) CEAI(p,8,10) CEAI(p,9,11) CEAI(p,12,14) CEAI(p,13,15) \
  CEAI(p,0,1) CEAI(p,2,3) CEAI(p,4,5) CEAI(p,6,7) CEAI(p,8,9) CEAI(p,10,11) CEAI(p,12,13) CEAI(p,14,15)

// bitonic cleanup: bitonic -> ascending (32 CE)
#define RESORT16I(p) \
  CEAI(p,0,8) CEAI(p,1,9) CEAI(p,2,10) CEAI(p,3,11) CEAI(p,4,12) CEAI(p,5,13) CEAI(p,6,14) CEAI(p,7,15) \
  CEAI(p,0,4) CEAI(p,1,5) CEAI(p,2,6) CEAI(p,3,7) CEAI(p,8,12) CEAI(p,9,13) CEAI(p,10,14) CEAI(p,11,15) \
  CEAI(p,0,2) CEAI(p,1,3) CEAI(p,4,6) CEAI(p,5,7) CEAI(p,8,10) CEAI(p,9,11) CEAI(p,12,14) CEAI(p,13,15) \
  CEAI(p,0,1) CEAI(p,2,3) CEAI(p,4,5) CEAI(p,6,7) CEAI(p,8,9) CEAI(p,10,11) CEAI(p,12,13) CEAI(p,14,15)

// keep 16 smallest of (sorted r) U (sorted x)
#define MERGE16I(r,x) \
  r##0=min(r##0,x##15); r##1=min(r##1,x##14); r##2=min(r##2,x##13); r##3=min(r##3,x##12); \
  r##4=min(r##4,x##11); r##5=min(r##5,x##10); r##6=min(r##6,x##9);  r##7=min(r##7,x##8);  \
  r##8=min(r##8,x##7);  r##9=min(r##9,x##6);  r##10=min(r##10,x##5); r##11=min(r##11,x##4); \
  r##12=min(r##12,x##3); r##13=min(r##13,x##2); r##14=min(r##14,x##1); r##15=min(r##15,x##0); \
  RESORT16I(r)

// folded distance: P.xyz = -2*bary_j, P.w = |bary_j|^2 ; q = (bary_i, |bary_i|^2)
__device__ __forceinline__ float distf(float4 q, float4 P) {
    return fmaf(q.x, P.x, fmaf(q.y, P.y, fmaf(q.z, P.z, q.w + P.w)));
}
// truncate mantissa to 9 bits, candidate index in low 14 bits
__device__ __forceinline__ int packkey(float d2, int j) {
    return (__float_as_int(d2) & 0xFFFFC000) | j;
}

// ---------------- Kernel 1: per-face prep ----------------
__global__ __launch_bounds__(BLK) void prep_kernel(
    const float* __restrict__ verts, const int* __restrict__ faces,
    float4* __restrict__ baryq, float4* __restrict__ baryqm,
    float* __restrict__ nrm, float* __restrict__ p0s, int F)
{
    int f = blockIdx.x * BLK + threadIdx.x;
    if (f >= F) return;
    int i0 = faces[3*f+0], i1 = faces[3*f+1], i2 = faces[3*f+2];
    float ax = verts[3*i0+0], ay = verts[3*i0+1], az = verts[3*i0+2];
    float bx = verts[3*i1+0], by = verts[3*i1+1], bz = verts[3*i1+2];
    float cx = verts[3*i2+0], cy = verts[3*i2+1], cz = verts[3*i2+2];
    float gx = (ax + bx + cx) / 3.0f;
    float gy = (ay + by + cy) / 3.0f;
    float gz = (az + bz + cz) / 3.0f;
    float sq = gx*gx + gy*gy + gz*gz;
    baryq[f]  = make_float4(gx, gy, gz, sq);
    baryqm[f] = make_float4(-2.0f*gx, -2.0f*gy, -2.0f*gz, sq);
    float e1x = bx-ax, e1y = by-ay, e1z = bz-az;
    float e2x = cx-ax, e2y = cy-ay, e2z = cz-az;
    float nx = e1y*e2z - e1z*e2y;
    float ny = e1z*e2x - e1x*e2z;
    float nz = e1x*e2y - e1y*e2x;
    float len = sqrtf(nx*nx + ny*ny + nz*nz);
    float dn = fmaxf(len, 1e-12f);
    nrm[3*f+0] = nx/dn; nrm[3*f+1] = ny/dn; nrm[3*f+2] = nz/dn;
    p0s[3*f+0] = ax; p0s[3*f+1] = ay; p0s[3*f+2] = az;
}

// -------- Kernel 2: sampled top-16 keys (LDS-staged candidates) ------------
__global__ __launch_bounds__(BLK) void knn_sample(
    const float4* __restrict__ baryq, const float4* __restrict__ baryqm,
    int* __restrict__ samp_k, int F, int SLEN)
{
    extern __shared__ float4 sb[];
    int tid = threadIdx.x;
    int qi = blockIdx.x * BLK + tid;
    float4 q = baryq[min(qi, F-1)];
    #define DECLR(m) int r##m = 0x7fffffff;
    REP16(DECLR)
    #undef DECLR
    int sbase = blockIdx.y * SLEN;
    if (tid < SLEN) {
        int j = (sbase + tid) * SSTRIDE;
        sb[tid] = (j < F) ? baryqm[j] : make_float4(0.f, 0.f, 0.f, INFINITY);
    }
    __syncthreads();
    #pragma unroll 1
    for (int g = 0; g < SLEN; g += 16) {
        #define MKK(m) int x##m = packkey(distf(q, sb[g+(m)]), (sbase+g+(m))*SSTRIDE);
        REP16(MKK)
        #undef MKK
        SORT16I(x)
        MERGE16I(r, x)
    }
    if (qi < F) {
        size_t cb = (size_t)blockIdx.y * KNN * F + qi;
        #define STR(m) samp_k[cb + (size_t)(m) * F] = r##m;
        REP16(STR)
        #undef STR
    }
}

// -------- Kernel 3: merge sample lists -> threshold key; zero cnt and out --
__global__ __launch_bounds__(BLK) void merge_T(
    const int* __restrict__ samp_k, int* __restrict__ Tkey,
    int* __restrict__ cnt, float* __restrict__ out, int F)
{
    int qi = blockIdx.x * BLK + threadIdx.x;
    if (blockIdx.x == 0 && threadIdx.x == 0) out[0] = 0.0f;
    if (qi >= F) return;
    #define LDR(m) int r##m = samp_k[(size_t)(m) * F + qi];
    REP16(LDR)
    #undef LDR
    for (int c = 1; c < SCH; ++c) {
        size_t cb = (size_t)c * KNN * F + qi;
        #define LDX(m) int x##m = samp_k[cb + (size_t)(m) * F];
        REP16(LDX)
        #undef LDX
        MERGE16I(r, x)
    }
    Tkey[qi] = r15;          // 16th-smallest sample key >= true 16th key
    cnt[qi] = 0;
}

// -------- Kernel 4: threshold collect; REGISTER stash (17 static slots) ----
// grid (qBlocks, nCChunk ~49). No LDS. Shift-insert only on survive (~8% of
// wave-steps, exec-masked). One atomicAdd + <=17 stores per (query,chunk).
__global__ __launch_bounds__(BLK, 6) void collect_kernel(
    const float4* __restrict__ baryq, const float4* __restrict__ baryqm,
    const int* __restrict__ Tkey, int* __restrict__ cnt,
    int* __restrict__ buf, int F, int CLEN, int CAP)
{
    int tid = threadIdx.x;
    int qi = blockIdx.x * BLK + tid;
    bool active = qi < F;
    int qc = min(qi, F-1);
    float4 q = baryq[qc];
    int T = active ? Tkey[qc] : 0x80000000;   // inactive lanes collect nothing
    #define DECLS(m) int s##m = 0;
    REP17(DECLS)
    #undef DECLS
    int lcnt = 0;
    // newest-first shift insert; slot order is irrelevant downstream
    #define SHIFT_INS(key) { \
        s16=s15; s15=s14; s14=s13; s13=s12; s12=s11; s11=s10; s10=s9; s9=s8; \
        s8=s7; s7=s6; s6=s5; s5=s4; s4=s3; s3=s2; s2=s1; s1=s0; s0=(key); ++lcnt; }
    int jb = blockIdx.y * CLEN;
    int je = min(jb + CLEN, F);
    int jfull = jb + ((je - jb) & ~15);
    #pragma unroll 1
    for (int base = jb; base < jfull; base += 16) {
        const float4* tp = baryqm + base;
        #define CSTEP(m) { float4 P = tp[m]; \
            int key = packkey(distf(q, P), base + (m)); \
            if (key <= T) SHIFT_INS(key) }
        REP16(CSTEP)
        #undef CSTEP
    }
    for (int j = jfull; j < je; ++j) {        // tail (F%16!=0 only)
        float4 P = baryqm[j];
        int key = packkey(distf(q, P), j);
        if (key <= T) SHIFT_INS(key)
    }
    #undef SHIFT_INS
    int lc = min(lcnt, RCAP);                 // overflow guard (P ~ 1e-8)
    if (active && lc > 0) {
        int basep = atomicAdd(&cnt[qi], lc);
        size_t rb = (size_t)qi * CAP;
        #define FLUSH(m) if ((m) < lc) { int p = basep + (m); \
            if (p < CAP) buf[rb + p] = s##m; }
        REP17(FLUSH)
        #undef FLUSH
    }
}

// -------- Kernel 5: fused exact top-16 + penetration + global reduce -------
__device__ __forceinline__ bool edge_test(
    float nx, float ny, float nz, float px, float py, float pz,
    float ax, float ay, float az, float bx, float by, float bz)
{
    float denom = nx*(bx-ax) + ny*(by-ay) + nz*(bz-az);
    if (fabsf(denom) < EPS_F) return false;
    float numer = nx*(px-ax) + ny*(py-ay) + nz*(pz-az);
    float t = numer / denom;
    return (t > 0.0f) && (t < 1.0f);
}

__global__ __launch_bounds__(BLK) void select_pen(
    const int* __restrict__ buf, const int* __restrict__ cnt,
    const float* __restrict__ verts, const int* __restrict__ faces,
    const float* __restrict__ prob, const float* __restrict__ nrm,
    const float* __restrict__ p0s, float* __restrict__ out,
    int F, int CAP)
{
    int qi = blockIdx.x * BLK + threadIdx.x;
    float val = 0.0f;
    if (qi < F) {
        int n = min(cnt[qi], CAP);
        const int* row = buf + (size_t)qi * CAP;
        #define DECLR(m) int r##m = 0x7fffffff;
        REP16(DECLR)
        #undef DECLR
        #pragma unroll 1
        for (int t = 0; t < n; t += 16) {
            #define LSEL(m) int x##m; { int v = row[t + (m)]; \
                x##m = (t + (m) < n) ? v : 0x7fffffff; }
            REP16(LSEL)
            #undef LSEL
            SORT16I(x)
            MERGE16I(r, x)
        }
        // penetration over the exact top-16 (#{key<=T} >= 16 by construction)
        float nx = nrm[3*qi+0], ny = nrm[3*qi+1], nz = nrm[3*qi+2];
        float px = p0s[3*qi+0], py = p0s[3*qi+1], pz = p0s[3*qi+2];
        #define PENM(m) { int j = r##m & 0x3FFF; \
            if (j != qi && j < F) { \
                int j0 = faces[3*j+0], j1 = faces[3*j+1], j2 = faces[3*j+2]; \
                float ax = verts[3*j0+0], ay = verts[3*j0+1], az = verts[3*j0+2]; \
                float bx = verts[3*j1+0], by = verts[3*j1+1], bz = verts[3*j1+2]; \
                float cx = verts[3*j2+0], cy = verts[3*j2+1], cz = verts[3*j2+2]; \
                bool hit = edge_test(nx,ny,nz, px,py,pz, ax,ay,az, bx,by,bz) \
                        || edge_test(nx,ny,nz, px,py,pz, bx,by,bz, cx,cy,cz) \
                        || edge_test(nx,ny,nz, px,py,pz, cx,cy,cz, ax,ay,az); \
                if (hit) val += prob[j]; } }
        REP16(PENM)
        #undef PENM
    }
    __shared__ float red[BLK];
    red[threadIdx.x] = val;
    __syncthreads();
    #pragma unroll
    for (int s = BLK/2; s > 0; s >>= 1) {
        if (threadIdx.x < s) red[threadIdx.x] += red[threadIdx.x + s];
        __syncthreads();
    }
    if (threadIdx.x == 0) atomicAdd(out, red[0] / (float)F);
}

extern "C" void kernel_launch(void* const* d_in, const int* in_sizes, int n_in,
                              void* d_out, int out_size, void* d_ws, size_t ws_size,
                              hipStream_t stream)
{
    const float* verts = (const float*)d_in[0];
    const int*   faces = (const int*)d_in[1];
    const float* prob  = (const float*)d_in[2];
    float* out = (float*)d_out;
    int F = in_sizes[2];

    size_t off = 0;
    auto carve = [&](size_t bytes) {
        size_t cur = off;
        off += (bytes + 255) & ~(size_t)255;
        return cur;
    };
    char* w = (char*)d_ws;
    int qBlocks = (F + BLK - 1) / BLK;
    float4* baryq  = (float4*)(w + carve((size_t)F * sizeof(float4)));
    float4* baryqm = (float4*)(w + carve((size_t)F * sizeof(float4)));
    float*  nrm    = (float*)(w + carve((size_t)F * 3 * sizeof(float)));
    float*  p0s    = (float*)(w + carve((size_t)F * 3 * sizeof(float)));
    int*    Tkey   = (int*)(w + carve((size_t)F * sizeof(int)));
    int*    cnt    = (int*)(w + carve((size_t)F * sizeof(int)));
    int*    samp_k = (int*)(w + carve((size_t)SCH * KNN * F * sizeof(int)));

    // survivor buffer: adaptive capacity from remaining ws (+pad for LSEL overread)
    size_t remain = (ws_size > off) ? (ws_size - off) : 0;
    int CAP = (int)((remain - 256) / ((size_t)F * sizeof(int)));
    if (CAP > 448) CAP = 448;
    if (CAP < 320) CAP = 320;
    CAP &= ~15;
    int* buf = (int*)(w + carve((size_t)F * CAP * sizeof(int) + 256));

    int nSamp = (F + SSTRIDE - 1) / SSTRIDE;
    int SLEN = ((nSamp + SCH - 1) / SCH + 15) & ~15;          // 160 at F=10000
    // collect grid: one scheduling round
    int nChTarget = (2048 / qBlocks > 1) ? (2048 / qBlocks) : 1; // 51 at F=10000
    int CLEN = (((F + nChTarget - 1) / nChTarget) + 15) & ~15;   // 208
    int nCChunk = (F + CLEN - 1) / CLEN;                         // 49

    prep_kernel<<<qBlocks, BLK, 0, stream>>>(verts, faces, baryq, baryqm, nrm, p0s, F);
    knn_sample<<<dim3(qBlocks, SCH), BLK, SLEN * sizeof(float4), stream>>>(
        baryq, baryqm, samp_k, F, SLEN);
    merge_T<<<qBlocks, BLK, 0, stream>>>(samp_k, Tkey, cnt, out, F);
    collect_kernel<<<dim3(qBlocks, nCChunk), BLK, 0, stream>>>(
        baryq, baryqm, Tkey, cnt, buf, F, CLEN, CAP);
    select_pen<<<qBlocks, BLK, 0, stream>>>(
        buf, cnt, verts, faces, prob, nrm, p0s, out, F, CAP);
}

// Round 11
// 85.644 us; speedup vs baseline: 1.7819x; 1.0554x over previous
//
#include <hip/hip_runtime.h>
#include <math.h>

#define KNN 16
#define EPS_F 0.001f
#define BLK 256
#define SCH 16             // sample chunks
#define SSTRIDE 8          // sample every 8th candidate

#define REP16(M) M(0) M(1) M(2) M(3) M(4) M(5) M(6) M(7) \
                 M(8) M(9) M(10) M(11) M(12) M(13) M(14) M(15)

// ---- int compare-exchange on packed keys (v_min_i32/v_max_i32) ----
#define CEAI(p,a,b) { int _lo = min(p##a, p##b); int _hi = max(p##a, p##b); p##a = _lo; p##b = _hi; }
#define CEDI(p,a,b) { int _lo = min(p##a, p##b); int _hi = max(p##a, p##b); p##a = _hi; p##b = _lo; }

// bitonic sort-16 ascending (80 CE)
#define SORT16I(p) \
  CEAI(p,0,1) CEDI(p,2,3) CEAI(p,4,5) CEDI(p,6,7) CEAI(p,8,9) CEDI(p,10,11) CEAI(p,12,13) CEDI(p,14,15) \
  CEAI(p,0,2) CEAI(p,1,3) CEDI(p,4,6) CEDI(p,5,7) CEAI(p,8,10) CEAI(p,9,11) CEDI(p,12,14) CEDI(p,13,15) \
  CEAI(p,0,1) CEAI(p,2,3) CEDI(p,4,5) CEDI(p,6,7) CEAI(p,8,9) CEAI(p,10,11) CEDI(p,12,13) CEDI(p,14,15) \
  CEAI(p,0,4) CEAI(p,1,5) CEAI(p,2,6) CEAI(p,3,7) CEDI(p,8,12) CEDI(p,9,13) CEDI(p,10,14) CEDI(p,11,15) \
  CEAI(p,0,2) CEAI(p,1,3) CEAI(p,4,6) CEAI(p,5,7) CEDI(p,8,10) CEDI(p,9,11) CEDI(p,12,14) CEDI(p,13,15) \
  CEAI(p,0,1) CEAI(p,2,3) CEAI(p,4,5) CEAI(p,6,7) CEDI(p,8,9) CEDI(p,10,11) CEDI(p,12,13) CEDI(p,14,15) \
  CEAI(p,0,8) CEAI(p,1,9) CEAI(p,2,10) CEAI(p,3,11) CEAI(p,4,12) CEAI(p,5,13) CEAI(p,6,14) CEAI(p,7,15) \
  CEAI(p,0,4) CEAI(p,1,5) CEAI(p,2,6) CEAI(p,3,7) CEAI(p,8,12) CEAI(p,9,13) CEAI(p,10,14) CEAI(p,11,15) \
  CEAI(p,0,2) CEAI(p,1,3) CEAI(p,4,6) CEAI(p,5,7) CEAI(p,8,10) CEAI(p,9,11) CEAI(p,12,14) CEAI(p,13,15) \
  CEAI(p,0,1) CEAI(p,2,3) CEAI(p,4,5) CEAI(p,6,7) CEAI(p,8,9) CEAI(p,10,11) CEAI(p,12,13) CEAI(p,14,15)

// bitonic cleanup: bitonic -> ascending (32 CE)
#define RESORT16I(p) \
  CEAI(p,0,8) CEAI(p,1,9) CEAI(p,2,10) CEAI(p,3,11) CEAI(p,4,12) CEAI(p,5,13) CEAI(p,6,14) CEAI(p,7,15) \
  CEAI(p,0,4) CEAI(p,1,5) CEAI(p,2,6) CEAI(p,3,7) CEAI(p,8,12) CEAI(p,9,13) CEAI(p,10,14) CEAI(p,11,15) \
  CEAI(p,0,2) CEAI(p,1,3) CEAI(p,4,6) CEAI(p,5,7) CEAI(p,8,10) CEAI(p,9,11) CEAI(p,12,14) CEAI(p,13,15) \
  CEAI(p,0,1) CEAI(p,2,3) CEAI(p,4,5) CEAI(p,6,7) CEAI(p,8,9) CEAI(p,10,11) CEAI(p,12,13) CEAI(p,14,15)

// keep 16 smallest of (sorted r) U (sorted x)
#define MERGE16I(r,x) \
  r##0=min(r##0,x##15); r##1=min(r##1,x##14); r##2=min(r##2,x##13); r##3=min(r##3,x##12); \
  r##4=min(r##4,x##11); r##5=min(r##5,x##10); r##6=min(r##6,x##9);  r##7=min(r##7,x##8);  \
  r##8=min(r##8,x##7);  r##9=min(r##9,x##6);  r##10=min(r##10,x##5); r##11=min(r##11,x##4); \
  r##12=min(r##12,x##3); r##13=min(r##13,x##2); r##14=min(r##14,x##1); r##15=min(r##15,x##0); \
  RESORT16I(r)

// folded distance: P.xyz = -2*bary_j, P.w = |bary_j|^2 ; q = (bary_i, |bary_i|^2)
__device__ __forceinline__ float distf(float4 q, float4 P) {
    return fmaf(q.x, P.x, fmaf(q.y, P.y, fmaf(q.z, P.z, q.w + P.w)));
}
// truncate mantissa to 9 bits, candidate index in low 14 bits
__device__ __forceinline__ int packkey(float d2, int j) {
    return (__float_as_int(d2) & 0xFFFFC000) | j;
}

// ---------------- Kernel 1: per-face prep ----------------
__global__ __launch_bounds__(BLK) void prep_kernel(
    const float* __restrict__ verts, const int* __restrict__ faces,
    float4* __restrict__ baryq, float4* __restrict__ baryqm,
    float* __restrict__ nrm, float* __restrict__ p0s, int F)
{
    int f = blockIdx.x * BLK + threadIdx.x;
    if (f >= F) return;
    int i0 = faces[3*f+0], i1 = faces[3*f+1], i2 = faces[3*f+2];
    float ax = verts[3*i0+0], ay = verts[3*i0+1], az = verts[3*i0+2];
    float bx = verts[3*i1+0], by = verts[3*i1+1], bz = verts[3*i1+2];
    float cx = verts[3*i2+0], cy = verts[3*i2+1], cz = verts[3*i2+2];
    float gx = (ax + bx + cx) / 3.0f;
    float gy = (ay + by + cy) / 3.0f;
    float gz = (az + bz + cz) / 3.0f;
    float sq = gx*gx + gy*gy + gz*gz;
    baryq[f]  = make_float4(gx, gy, gz, sq);
    baryqm[f] = make_float4(-2.0f*gx, -2.0f*gy, -2.0f*gz, sq);
    float e1x = bx-ax, e1y = by-ay, e1z = bz-az;
    float e2x = cx-ax, e2y = cy-ay, e2z = cz-az;
    float nx = e1y*e2z - e1z*e2y;
    float ny = e1z*e2x - e1x*e2z;
    float nz = e1x*e2y - e1y*e2x;
    float len = sqrtf(nx*nx + ny*ny + nz*nz);
    float dn = fmaxf(len, 1e-12f);
    nrm[3*f+0] = nx/dn; nrm[3*f+1] = ny/dn; nrm[3*f+2] = nz/dn;
    p0s[3*f+0] = ax; p0s[3*f+1] = ay; p0s[3*f+2] = az;
}

// -------- Kernel 2: sampled top-16 keys (LDS-staged; SCH=16 for TLP) -------
__global__ __launch_bounds__(BLK) void knn_sample(
    const float4* __restrict__ baryq, const float4* __restrict__ baryqm,
    int* __restrict__ samp_k, int F, int SLEN)
{
    extern __shared__ float4 sb[];
    int tid = threadIdx.x;
    int qi = blockIdx.x * BLK + tid;
    float4 q = baryq[min(qi, F-1)];
    #define DECLR(m) int r##m = 0x7fffffff;
    REP16(DECLR)
    #undef DECLR
    int sbase = blockIdx.y * SLEN;
    if (tid < SLEN) {
        int j = (sbase + tid) * SSTRIDE;
        sb[tid] = (j < F) ? baryqm[j] : make_float4(0.f, 0.f, 0.f, INFINITY);
    }
    __syncthreads();
    #pragma unroll 1
    for (int g = 0; g < SLEN; g += 16) {
        #define MKK(m) int x##m = packkey(distf(q, sb[g+(m)]), (sbase+g+(m))*SSTRIDE);
        REP16(MKK)
        #undef MKK
        SORT16I(x)
        MERGE16I(r, x)
    }
    if (qi < F) {
        size_t cb = (size_t)blockIdx.y * KNN * F + qi;
        #define STR(m) samp_k[cb + (size_t)(m) * F] = r##m;
        REP16(STR)
        #undef STR
    }
}

// -------- Kernel 3: merge sample lists -> threshold key; zero cnt and out --
__global__ __launch_bounds__(BLK) void merge_T(
    const int* __restrict__ samp_k, int* __restrict__ Tkey,
    int* __restrict__ cnt, float* __restrict__ out, int F)
{
    int qi = blockIdx.x * BLK + threadIdx.x;
    if (blockIdx.x == 0 && threadIdx.x == 0) out[0] = 0.0f;
    if (qi >= F) return;
    #define LDR(m) int r##m = samp_k[(size_t)(m) * F + qi];
    REP16(LDR)
    #undef LDR
    #pragma unroll 2
    for (int c = 1; c < SCH; ++c) {
        size_t cb = (size_t)c * KNN * F + qi;
        #define LDX(m) int x##m = samp_k[cb + (size_t)(m) * F];
        REP16(LDX)
        #undef LDX
        MERGE16I(r, x)
    }
    Tkey[qi] = r15;          // 16th-smallest sample key >= true 16th key
    cnt[qi] = 0;
}

// -------- Kernel 4: threshold collect; 8-deep register stash + mid-flush ---
// Hot path: 1 v_cmp_le_i32 on raw d bits vs Tup = T|0x3FFF (superset of
// key<=T with identical truncated-d; exact top-16 filter happens in select_pen).
// Survive path (~56% of wave-steps): packkey + 8-slot shift. Flush at 8 (exact).
__global__ __launch_bounds__(BLK, 8) void collect_kernel(
    const float4* __restrict__ baryq, const float4* __restrict__ baryqm,
    const int* __restrict__ Tkey, int* __restrict__ cnt,
    int* __restrict__ buf, int F, int CLEN, int CAP)
{
    int tid = threadIdx.x;
    int qi = blockIdx.x * BLK + tid;
    bool active = qi < F;
    int qc = min(qi, F-1);
    float4 q = baryq[qc];
    int T = active ? Tkey[qc] : 0x80000000;   // inactive: collects ~nothing; flush guarded
    int Tup = T | 0x3FFF;
    int s0=0,s1=0,s2=0,s3=0,s4=0,s5=0,s6=0,s7=0;
    int lcnt = 0;
    size_t rb = (size_t)qi * CAP;
    #define SHIFT_INS(keyv) { \
        s7=s6; s6=s5; s5=s4; s4=s3; s3=s2; s2=s1; s1=s0; s0=(keyv); \
        if (++lcnt == 8 && active) { \
            int bp = atomicAdd(&cnt[qi], 8); \
            if (bp + 8 <= CAP) { \
                buf[rb+bp+0]=s0; buf[rb+bp+1]=s1; buf[rb+bp+2]=s2; buf[rb+bp+3]=s3; \
                buf[rb+bp+4]=s4; buf[rb+bp+5]=s5; buf[rb+bp+6]=s6; buf[rb+bp+7]=s7; } \
            lcnt = 0; } }
    int jb = blockIdx.y * CLEN;
    int je = min(jb + CLEN, F);
    int jfull = jb + ((je - jb) & ~15);
    #pragma unroll 1
    for (int base = jb; base < jfull; base += 16) {
        const float4* tp = baryqm + base;
        #define CSTEP(m) { float4 P = tp[m]; \
            float d = distf(q, P); \
            if (__float_as_int(d) <= Tup) { \
                int key = packkey(d, base + (m)); \
                SHIFT_INS(key) } }
        REP16(CSTEP)
        #undef CSTEP
    }
    for (int j = jfull; j < je; ++j) {        // tail (F%16!=0 only)
        float4 P = baryqm[j];
        float d = distf(q, P);
        if (__float_as_int(d) <= Tup) {
            int key = packkey(d, j);
            SHIFT_INS(key)
        }
    }
    #undef SHIFT_INS
    if (active && lcnt > 0) {                 // lcnt < 8 here (flush resets at 8)
        int bp = atomicAdd(&cnt[qi], lcnt);
        #define FLUSH(m) if ((m) < lcnt && bp + (m) < CAP) buf[rb + bp + (m)] = s##m;
        FLUSH(0) FLUSH(1) FLUSH(2) FLUSH(3) FLUSH(4) FLUSH(5) FLUSH(6) FLUSH(7)
        #undef FLUSH
    }
}

// -------- Kernel 5: fused exact top-16 + penetration + global reduce -------
__device__ __forceinline__ bool edge_test(
    float nx, float ny, float nz, float px, float py, float pz,
    float ax, float ay, float az, float bx, float by, float bz)
{
    float denom = nx*(bx-ax) + ny*(by-ay) + nz*(bz-az);
    if (fabsf(denom) < EPS_F) return false;
    float numer = nx*(px-ax) + ny*(py-ay) + nz*(pz-az);
    float t = numer / denom;
    return (t > 0.0f) && (t < 1.0f);
}

__global__ __launch_bounds__(BLK) void select_pen(
    const int* __restrict__ buf, const int* __restrict__ cnt,
    const float* __restrict__ verts, const int* __restrict__ faces,
    const float* __restrict__ prob, const float* __restrict__ nrm,
    const float* __restrict__ p0s, float* __restrict__ out,
    int F, int CAP)
{
    int qi = blockIdx.x * BLK + threadIdx.x;
    float val = 0.0f;
    if (qi < F) {
        int n = min(cnt[qi], CAP);
        const int* row = buf + (size_t)qi * CAP;
        #define DECLR(m) int r##m = 0x7fffffff;
        REP16(DECLR)
        #undef DECLR
        #pragma unroll 1
        for (int t = 0; t < n; t += 16) {
            #define LSEL(m) int x##m; { int v = row[t + (m)]; \
                x##m = (t + (m) < n) ? v : 0x7fffffff; }
            REP16(LSEL)
            #undef LSEL
            SORT16I(x)
            MERGE16I(r, x)
        }
        // penetration over the exact top-16 (#{key<=T} >= 16 by construction)
        float nx = nrm[3*qi+0], ny = nrm[3*qi+1], nz = nrm[3*qi+2];
        float px = p0s[3*qi+0], py = p0s[3*qi+1], pz = p0s[3*qi+2];
        #define PENM(m) { int j = r##m & 0x3FFF; \
            if (j != qi && j < F) { \
                int j0 = faces[3*j+0], j1 = faces[3*j+1], j2 = faces[3*j+2]; \
                float ax = verts[3*j0+0], ay = verts[3*j0+1], az = verts[3*j0+2]; \
                float bx = verts[3*j1+0], by = verts[3*j1+1], bz = verts[3*j1+2]; \
                float cx = verts[3*j2+0], cy = verts[3*j2+1], cz = verts[3*j2+2]; \
                bool hit = edge_test(nx,ny,nz, px,py,pz, ax,ay,az, bx,by,bz) \
                        || edge_test(nx,ny,nz, px,py,pz, bx,by,bz, cx,cy,cz) \
                        || edge_test(nx,ny,nz, px,py,pz, cx,cy,cz, ax,ay,az); \
                if (hit) val += prob[j]; } }
        REP16(PENM)
        #undef PENM
    }
    __shared__ float red[BLK];
    red[threadIdx.x] = val;
    __syncthreads();
    #pragma unroll
    for (int s = BLK/2; s > 0; s >>= 1) {
        if (threadIdx.x < s) red[threadIdx.x] += red[threadIdx.x + s];
        __syncthreads();
    }
    if (threadIdx.x == 0) atomicAdd(out, red[0] / (float)F);
}

extern "C" void kernel_launch(void* const* d_in, const int* in_sizes, int n_in,
                              void* d_out, int out_size, void* d_ws, size_t ws_size,
                              hipStream_t stream)
{
    const float* verts = (const float*)d_in[0];
    const int*   faces = (const int*)d_in[1];
    const float* prob  = (const float*)d_in[2];
    float* out = (float*)d_out;
    int F = in_sizes[2];

    size_t off = 0;
    auto carve = [&](size_t bytes) {
        size_t cur = off;
        off += (bytes + 255) & ~(size_t)255;
        return cur;
    };
    char* w = (char*)d_ws;
    int qBlocks = (F + BLK - 1) / BLK;
    float4* baryq  = (float4*)(w + carve((size_t)F * sizeof(float4)));
    float4* baryqm = (float4*)(w + carve((size_t)F * sizeof(float4)));
    float*  nrm    = (float*)(w + carve((size_t)F * 3 * sizeof(float)));
    float*  p0s    = (float*)(w + carve((size_t)F * 3 * sizeof(float)));
    int*    Tkey   = (int*)(w + carve((size_t)F * sizeof(int)));
    int*    cnt    = (int*)(w + carve((size_t)F * sizeof(int)));
    int*    samp_k = (int*)(w + carve((size_t)SCH * KNN * F * sizeof(int)));

    // survivor buffer: adaptive capacity from remaining ws (+pad for LSEL overread)
    size_t remain = (ws_size > off) ? (ws_size - off) : 0;
    int CAP = (int)((remain - 256) / ((size_t)F * sizeof(int)));
    if (CAP > 448) CAP = 448;
    if (CAP < 320) CAP = 320;
    CAP &= ~15;
    int* buf = (int*)(w + carve((size_t)F * CAP * sizeof(int) + 256));

    int nSamp = (F + SSTRIDE - 1) / SSTRIDE;
    int SLEN = ((nSamp + SCH - 1) / SCH + 15) & ~15;          // 80 at F=10000
    // collect grid: one scheduling round (8 blocks/CU x 256 CU = 2048)
    int nChTarget = (2048 / qBlocks > 1) ? (2048 / qBlocks) : 1; // 51 at F=10000
    int CLEN = (((F + nChTarget - 1) / nChTarget) + 15) & ~15;   // 208
    int nCChunk = (F + CLEN - 1) / CLEN;                         // 49

    prep_kernel<<<qBlocks, BLK, 0, stream>>>(verts, faces, baryq, baryqm, nrm, p0s, F);
    knn_sample<<<dim3(qBlocks, SCH), BLK, SLEN * sizeof(float4), stream>>>(
        baryq, baryqm, samp_k, F, SLEN);
    merge_T<<<qBlocks, BLK, 0, stream>>>(samp_k, Tkey, cnt, out, F);
    collect_kernel<<<dim3(qBlocks, nCChunk), BLK, 0, stream>>>(
        baryq, baryqm, Tkey, cnt, buf, F, CLEN, CAP);
    select_pen<<<qBlocks, BLK, 0, stream>>>(
        buf, cnt, verts, faces, prob, nrm, p0s, out, F, CAP);
}